// Round 4
// baseline (299.456 us; speedup 1.0000x reference)
//
#include <hip/hip_runtime.h>
#include <math.h>
#include <string.h>

#define CDIM 64
#define LDSW 72   // row stride in bf16 elems (144 B): b128 frag reads measured conflict-free
#define DEG  5    // Chebyshev tail on [1,7.5] ~5.6e-3; Paterson-Stockmeyer s=2 -> 3 matmuls
#define GRID 1024 // 4 blocks/CU x 256 CU: fully resident persistent grid

struct Coefs { float a[DEG + 1]; float cc; float inv_h; };

typedef __attribute__((ext_vector_type(8)))  short short8;    // 8 bf16 = 4 VGPRs (MFMA A/B frag)
typedef __attribute__((ext_vector_type(16))) float floatx16;  // MFMA C/D

// Fused waitcnt+barrier in ONE asm blob with memory clobber:
//  - lgkmcnt(0) publishes this wave's ds_writes before the barrier
//  - single-asm form: post-barrier ds_reads cannot hoist between wait and barrier
//  - does NOT drain vmcnt: global prefetch loads / output stores stay in flight
//    across phases (the whole point vs __syncthreads' vmcnt(0) drain)
#define LBAR() asm volatile("s_waitcnt lgkmcnt(0)\n\ts_barrier" ::: "memory")

// Row-major hi/lo store of one fp32 as two bf16 (truncation split).
// Per instruction: half-wave writes 32 consecutive u16 of row q, other half
// row q+4 -> in-dword lane merge: 0 conflicts (measured R2).
__device__ __forceinline__ void st_hilo(unsigned short* __restrict__ Dh,
                                        unsigned short* __restrict__ Dl,
                                        int idx, float x) {
  const unsigned u = __builtin_bit_cast(unsigned, x);
  const float h = __builtin_bit_cast(float, u & 0xFFFF0000u);
  const float l = x - h;                       // exact
  const unsigned ul = __builtin_bit_cast(unsigned, l);
  Dh[idx] = (unsigned short)(u >> 16);
  Dl[idx] = (unsigned short)(ul >> 16);
}

// Scalar hi/lo read back to f32 (~2^-17 rel error vs stored value).
__device__ __forceinline__ float ld_hilo(const unsigned short* __restrict__ Ph,
                                         const unsigned short* __restrict__ Pl,
                                         int idx) {
  const float h = __builtin_bit_cast(float, ((unsigned)Ph[idx]) << 16);
  const float l = __builtin_bit_cast(float, ((unsigned)Pl[idx]) << 16);
  return h + l;
}

struct Frags { short8 h[4]; short8 l[4]; };    // 4 K-slabs of hi+lo fragments = 32 VGPRs

__device__ __forceinline__ void load_frags(const unsigned short* __restrict__ Ph,
                                           const unsigned short* __restrict__ Pl,
                                           int row, int ko, Frags* f) {
#pragma unroll
  for (int kk = 0; kk < 4; ++kk) {
    f->h[kk] = *(const short8*)(Ph + row * LDSW + kk * 16 + ko);
    f->l[kk] = *(const short8*)(Pl + row * LDSW + kk * 16 + ko);
  }
}

// 32x32 tile product, compensated split on TWO acc chains (hh) and (hl+lh).
// setprio(1) around the MFMA cluster: independent blocks sit at different
// phases on a CU, so the scheduler can favor the MFMA-issuing wave (T5 regime).
__device__ __forceinline__ floatx16 mm_frags(const Frags& a, const Frags& b) {
  floatx16 c1, c2;
#pragma unroll
  for (int i = 0; i < 16; ++i) { c1[i] = 0.0f; c2[i] = 0.0f; }
  __builtin_amdgcn_s_setprio(1);
#pragma unroll
  for (int kk = 0; kk < 4; ++kk) {
    c1 = __builtin_amdgcn_mfma_f32_32x32x16_bf16(a.h[kk], b.h[kk], c1, 0, 0, 0);
    c2 = __builtin_amdgcn_mfma_f32_32x32x16_bf16(a.h[kk], b.l[kk], c2, 0, 0, 0);
    c2 = __builtin_amdgcn_mfma_f32_32x32x16_bf16(a.l[kk], b.h[kk], c2, 0, 0, 0);
  }
  __builtin_amdgcn_s_setprio(0);
#pragma unroll
  for (int i = 0; i < 16; ++i) c1[i] += c2[i];
  return c1;
}

__global__ void __launch_bounds__(256, 4)
logm_kernel(const float* __restrict__ X, float* __restrict__ Y, int nmat, Coefs cf) {
  // Buffers: A = M1 (then next M1), C = M2 then Q1.  36.9 KB -> 4 blocks/CU.
  // Persistent pipeline per iteration:
  //   P1: fa,fb<-A, M2=M1*M1 -> C; issue global prefetch x(next)   | LBAR
  //   P2: fm2<-C, T=M1*M2 (fa reused); rE=M1 scalars; fold Q1 vals | LBAR
  //   P3: Q1 -> C ; M1(next) -> A (from prefetch regs)             | LBAR
  //   P4: fq1<-C, out=Q1*M2+a1*M1+a0*I -> global                   | LBAR
  // Register plan: fa dies slab-wise in P2 as fm2 arrives; accM2 not carried
  // (a4*M2 re-read from C); rE read once, used for a3 and a1 terms.
  __shared__ __align__(16) unsigned short Ah[CDIM * LDSW], Al[CDIM * LDSW];
  __shared__ __align__(16) unsigned short Ch[CDIM * LDSW], Cl[CDIM * LDSW];

  const int tid  = threadIdx.x;
  const int lane = tid & 63;
  const int w    = tid >> 6;

  const int R    = (w >> 1) * 32;
  const int Cc   = (w & 1) * 32;
  const int l31  = lane & 31;
  const int half = lane >> 5;
  const int arow = R + l31;
  const int brow = Cc + l31;
  const int ko   = half * 8;
  const int col  = Cc + l31;
  int rows[16];  // C/D layout: row = (r&3) + 8*(r>>2) + 4*half  [verified m74/m101]
#pragma unroll
  for (int r = 0; r < 16; ++r) rows[r] = R + (r & 3) + 8 * (r >> 2) + 4 * half;

  int m = blockIdx.x;
  if (m >= nmat) return;   // uniform block exit, before any barrier

  // ---- prologue: stage M1(first) -> A ----
  {
    const float* __restrict__ Xm = X + (size_t)m * (CDIM * CDIM);
#pragma unroll
    for (int r = 0; r < 16; ++r) {
      float x = Xm[rows[r] * CDIM + col];
      if (rows[r] == col) x -= cf.cc;
      st_hilo(Ah, Al, rows[r] * LDSW + col, x * cf.inv_h);
    }
  }
  LBAR();

  for (; m < nmat; m += GRID) {
    const int mn = m + GRID;
    float* __restrict__ Ym = Y + (size_t)m * (CDIM * CDIM);

    // ---- P1: M2 = M1*M1 -> C ----
    Frags fa, fb;
    load_frags(Ah, Al, arow, ko, &fa);
    if (R == Cc) fb = fa; else load_frags(Ah, Al, brow, ko, &fb);  // wave-uniform
    floatx16 accM2 = mm_frags(fa, fb);
    // prefetch next matrix AFTER the mfma (fb dead -> low reg peak); the
    // ~900cy HBM latency hides under the rest of P1 + P2 (loads consumed in P3)
    float xpf[16];
    {
      const float* __restrict__ Xn = X + (size_t)(mn < nmat ? mn : m) * (CDIM * CDIM);
#pragma unroll
      for (int r = 0; r < 16; ++r) xpf[r] = Xn[rows[r] * CDIM + col];
    }
#pragma unroll
    for (int r = 0; r < 16; ++r) st_hilo(Ch, Cl, rows[r] * LDSW + col, accM2[r]);
    LBAR();  // M2 published

    // ---- P2: T = M1*M2 (fa reused as M1 A-rows); fold Q1 = a5*T + a4*M2 + a3*M1 + a2*I ----
    Frags fm2;
    load_frags(Ch, Cl, brow, ko, &fm2);    // M2 B-operand via symmetry; kept for P4
    floatx16 accT = mm_frags(fa, fm2);
    float rE[16];                           // M1 scalars: a3 term now, a1 term in P4
#pragma unroll
    for (int r = 0; r < 16; ++r) {
      const int idx = rows[r] * LDSW + col;
      rE[r] = ld_hilo(Ah, Al, idx);
      float q = cf.a[5] * accT[r] + cf.a[4] * ld_hilo(Ch, Cl, idx) + cf.a[3] * rE[r];
      if (rows[r] == col) q += cf.a[2];
      accT[r] = q;                          // reuse accT as Q1 carrier
    }
    LBAR();  // all A (M1) and C (M2) reads complete

    // ---- P3: Q1 -> C ; M1(next) -> A ----
#pragma unroll
    for (int r = 0; r < 16; ++r) st_hilo(Ch, Cl, rows[r] * LDSW + col, accT[r]);
    if (mn < nmat) {                        // block-uniform
#pragma unroll
      for (int r = 0; r < 16; ++r) {
        float x = xpf[r];
        if (rows[r] == col) x -= cf.cc;
        st_hilo(Ah, Al, rows[r] * LDSW + col, x * cf.inv_h);
      }
    }
    LBAR();  // Q1 and next M1 published

    // ---- P4: out = Q1*M2 + a1*M1 + a0*I -> global (2x128B coalesced per instr) ----
    Frags fq1;
    load_frags(Ch, Cl, arow, ko, &fq1);
    floatx16 accF = mm_frags(fq1, fm2);
#pragma unroll
    for (int r = 0; r < 16; ++r) {
      float p = accF[r] + cf.a[1] * rE[r];
      if (rows[r] == col) p += cf.a[0];
      Ym[rows[r] * CDIM + col] = p;         // stores drain lazily (no vmcnt at LBAR)
    }
    LBAR();  // C (Q1) reads done before next P1 overwrites C
  }
}

extern "C" void kernel_launch(void* const* d_in, const int* in_sizes, int n_in,
                              void* d_out, int out_size, void* d_ws, size_t ws_size,
                              hipStream_t stream) {
  const float* X = (const float*)d_in[0];
  float* Y = (float*)d_out;
  const int nmat = in_sizes[0] / (CDIM * CDIM);

  // Chebyshev coefficients of log on [lo,hi] -> monomial basis in t=(x-cc)/hh.
  // Analytic: log(cc+hh*t) = log(A) - 2*sum_k z^k/k T_k(t),  z=(-cc+sqrt(cc^2-hh^2))/hh
  Coefs cf;
  {
    const double lo = 1.0, hi = 7.5;
    const double cc = 0.5 * (lo + hi), hh = 0.5 * (hi - lo);
    const double s  = sqrt(cc * cc - hh * hh);
    const double z  = (-cc + s) / hh;
    const double A  = 0.5 * (cc + s);
    double cheb[DEG + 1];
    cheb[0] = log(A);
    double zp = 1.0;
    for (int k = 1; k <= DEG; ++k) { zp *= z; cheb[k] = -2.0 * zp / (double)k; }
    double mono[DEG + 1], Tprev[DEG + 1], Tcur[DEG + 1];
    memset(mono, 0, sizeof(mono));
    memset(Tprev, 0, sizeof(Tprev));
    memset(Tcur, 0, sizeof(Tcur));
    Tprev[0] = 1.0; mono[0] += cheb[0];
    Tcur[1]  = 1.0; mono[1] += cheb[1];
    for (int k = 2; k <= DEG; ++k) {
      double Tn[DEG + 1];
      memset(Tn, 0, sizeof(Tn));
      for (int j = 0; j <= k; ++j) {
        double v = -Tprev[j];
        if (j > 0) v += 2.0 * Tcur[j - 1];
        Tn[j] = v;
      }
      for (int j = 0; j <= k; ++j) mono[j] += cheb[k] * Tn[j];
      for (int j = 0; j <= DEG; ++j) { Tprev[j] = Tcur[j]; Tcur[j] = Tn[j]; }
    }
    for (int i = 0; i <= DEG; ++i) cf.a[i] = (float)mono[i];
    cf.cc = (float)cc; cf.inv_h = (float)(1.0 / hh);
  }

  const int nblk = nmat < GRID ? nmat : GRID;
  dim3 grid(nblk), block(256);
  hipLaunchKernelGGL(logm_kernel, grid, block, 0, stream, X, Y, nmat, cf);
}

// Round 5
// 217.926 us; speedup vs baseline: 1.3741x; 1.3741x over previous
//
#include <hip/hip_runtime.h>
#include <math.h>
#include <string.h>

#define CDIM 64
#define LDSW 72   // row stride in bf16 elems (144 B): b128 frag reads measured conflict-free
#define DEG  5    // Chebyshev tail on [1,7.5] ~5.6e-3; Paterson-Stockmeyer s=2 -> 3 matmuls

struct Coefs { float a[DEG + 1]; float cc; float inv_h; };

typedef __attribute__((ext_vector_type(8)))  short short8;    // 8 bf16 = 4 VGPRs (MFMA A/B frag)
typedef __attribute__((ext_vector_type(16))) float floatx16;  // MFMA C/D

// Fused lgkm-wait + barrier in ONE asm blob (memory clobber):
//  - publishes this wave's ds_writes / completes its ds_reads before the barrier
//  - does NOT drain vmcnt like __syncthreads (no cross-barrier global hazards here:
//    stage loads are consumed in-phase, output stores drain at endpgm)
#define LBAR() asm volatile("s_waitcnt lgkmcnt(0)\n\ts_barrier" ::: "memory")

// Row-major hi/lo store of one fp32 as two bf16 (truncation split).
// Per instruction: half-wave writes 32 consecutive u16 of row q, other half
// row q+4 -> in-dword lane merge: 0 conflicts (measured R2).
__device__ __forceinline__ void st_hilo(unsigned short* __restrict__ Dh,
                                        unsigned short* __restrict__ Dl,
                                        int idx, float x) {
  const unsigned u = __builtin_bit_cast(unsigned, x);
  const float h = __builtin_bit_cast(float, u & 0xFFFF0000u);
  const float l = x - h;                       // exact
  const unsigned ul = __builtin_bit_cast(unsigned, l);
  Dh[idx] = (unsigned short)(u >> 16);
  Dl[idx] = (unsigned short)(ul >> 16);
}

// Scalar hi/lo read back to f32 (~2^-17 rel error vs stored value).
__device__ __forceinline__ float ld_hilo(const unsigned short* __restrict__ Ph,
                                         const unsigned short* __restrict__ Pl,
                                         int idx) {
  const float h = __builtin_bit_cast(float, ((unsigned)Ph[idx]) << 16);
  const float l = __builtin_bit_cast(float, ((unsigned)Pl[idx]) << 16);
  return h + l;
}

struct Frags { short8 h[4]; short8 l[4]; };    // 4 K-slabs of hi+lo fragments = 32 VGPRs

__device__ __forceinline__ void load_frags(const unsigned short* __restrict__ Ph,
                                           const unsigned short* __restrict__ Pl,
                                           int row, int ko, Frags* f) {
#pragma unroll
  for (int kk = 0; kk < 4; ++kk) {
    f->h[kk] = *(const short8*)(Ph + row * LDSW + kk * 16 + ko);
    f->l[kk] = *(const short8*)(Pl + row * LDSW + kk * 16 + ko);
  }
}

// 32x32 tile product, compensated split on TWO acc chains (hh) and (hl+lh).
// setprio(1) around the MFMA cluster: 4 independent blocks/CU sit at different
// phases (T5's role-split regime, +4-7% measured on attn-like schedules).
__device__ __forceinline__ floatx16 mm_frags(const Frags& a, const Frags& b) {
  floatx16 c1, c2;
#pragma unroll
  for (int i = 0; i < 16; ++i) { c1[i] = 0.0f; c2[i] = 0.0f; }
  __builtin_amdgcn_s_setprio(1);
#pragma unroll
  for (int kk = 0; kk < 4; ++kk) {
    c1 = __builtin_amdgcn_mfma_f32_32x32x16_bf16(a.h[kk], b.h[kk], c1, 0, 0, 0);
    c2 = __builtin_amdgcn_mfma_f32_32x32x16_bf16(a.h[kk], b.l[kk], c2, 0, 0, 0);
    c2 = __builtin_amdgcn_mfma_f32_32x32x16_bf16(a.l[kk], b.h[kk], c2, 0, 0, 0);
  }
  __builtin_amdgcn_s_setprio(0);
#pragma unroll
  for (int i = 0; i < 16; ++i) c1[i] += c2[i];
  return c1;
}

__global__ void __launch_bounds__(256, 4)
logm_kernel(const float* __restrict__ X, float* __restrict__ Y, Coefs cf) {
  // Buffers: A = M1 (never overwritten), C = M2 then Q1.  36.9 KB -> 4 blocks/CU.
  // R5 = verified R2 schedule + {fa-reuse in mm2, lgkm-only barriers, setprio}.
  // Register headroom lesson (R1/R4): live set ~112 of 128; any +16-reg addition
  // spills (symmetric FETCH/WRITE balloon). All R5 changes are register-neutral.
  __shared__ __align__(16) unsigned short Ah[CDIM * LDSW], Al[CDIM * LDSW];
  __shared__ __align__(16) unsigned short Ch[CDIM * LDSW], Cl[CDIM * LDSW];

  const int tid  = threadIdx.x;
  const int lane = tid & 63;
  const int w    = tid >> 6;
  const int m    = blockIdx.x;

  const float* __restrict__ Xm = X + (size_t)m * (CDIM * CDIM);
  float* __restrict__ Ym       = Y + (size_t)m * (CDIM * CDIM);

  const int R    = (w >> 1) * 32;
  const int Cc   = (w & 1) * 32;
  const int l31  = lane & 31;
  const int half = lane >> 5;
  const int arow = R + l31;
  const int brow = Cc + l31;
  const int ko   = half * 8;
  const int col  = Cc + l31;
  int rows[16];  // C/D layout: row = (r&3) + 8*(r>>2) + 4*half  [verified m74/m101]
#pragma unroll
  for (int r = 0; r < 16; ++r) rows[r] = R + (r & 3) + 8 * (r >> 2) + 4 * half;

  // ---- stage: load X once in C-layout (coalesced 2x128B per instr), M1 -> A ----
#pragma unroll
  for (int r = 0; r < 16; ++r) {
    float x = Xm[rows[r] * CDIM + col];
    if (rows[r] == col) x -= cf.cc;
    st_hilo(Ah, Al, rows[r] * LDSW + col, x * cf.inv_h);
  }
  LBAR();

  // ---- mm1: M2 = M1*M1 -> C; keep accM2 (f32, AGPRs) for the a4*M2 term;
  //      keep fa live: it is mm2's A-operand (A untouched in between) ----
  Frags fa, fb;
  load_frags(Ah, Al, arow, ko, &fa);
  if (R == Cc) fb = fa; else load_frags(Ah, Al, brow, ko, &fb);  // wave-uniform branch
  floatx16 accM2 = mm_frags(fa, fb);
#pragma unroll
  for (int r = 0; r < 16; ++r) st_hilo(Ch, Cl, rows[r] * LDSW + col, accM2[r]);
  LBAR();

  // ---- mm2: T = M1*M2 (fa reused, no fm1 reload); Q1 = a5*T + a4*M2 + a3*M1 + a2*I ----
  Frags fm2;
  load_frags(Ch, Cl, brow, ko, &fm2);    // M2 B-operand via symmetry; kept in regs for mm3
  floatx16 accT = mm_frags(fa, fm2);
  LBAR();                                // all C (M2) cross-tile reads complete
#pragma unroll
  for (int r = 0; r < 16; ++r) {
    const int idx = rows[r] * LDSW + col;
    float q = cf.a[5] * accT[r] + cf.a[4] * accM2[r] + cf.a[3] * ld_hilo(Ah, Al, idx);
    if (rows[r] == col) q += cf.a[2];
    st_hilo(Ch, Cl, idx, q);             // Q1 over M2
  }
  LBAR();

  // ---- mm3: out = Q1*M2 + a1*M1 + a0*I -> global (2x128B coalesced per instr) ----
  Frags fq1;
  load_frags(Ch, Cl, arow, ko, &fq1);
  floatx16 accF = mm_frags(fq1, fm2);
#pragma unroll
  for (int r = 0; r < 16; ++r) {
    float p = accF[r] + cf.a[1] * ld_hilo(Ah, Al, rows[r] * LDSW + col);
    if (rows[r] == col) p += cf.a[0];
    Ym[rows[r] * CDIM + col] = p;
  }
}

extern "C" void kernel_launch(void* const* d_in, const int* in_sizes, int n_in,
                              void* d_out, int out_size, void* d_ws, size_t ws_size,
                              hipStream_t stream) {
  const float* X = (const float*)d_in[0];
  float* Y = (float*)d_out;
  const int nmat = in_sizes[0] / (CDIM * CDIM);

  // Chebyshev coefficients of log on [lo,hi] -> monomial basis in t=(x-cc)/hh.
  // Analytic: log(cc+hh*t) = log(A) - 2*sum_k z^k/k T_k(t),  z=(-cc+sqrt(cc^2-hh^2))/hh
  Coefs cf;
  {
    const double lo = 1.0, hi = 7.5;
    const double cc = 0.5 * (lo + hi), hh = 0.5 * (hi - lo);
    const double s  = sqrt(cc * cc - hh * hh);
    const double z  = (-cc + s) / hh;
    const double A  = 0.5 * (cc + s);
    double cheb[DEG + 1];
    cheb[0] = log(A);
    double zp = 1.0;
    for (int k = 1; k <= DEG; ++k) { zp *= z; cheb[k] = -2.0 * zp / (double)k; }
    double mono[DEG + 1], Tprev[DEG + 1], Tcur[DEG + 1];
    memset(mono, 0, sizeof(mono));
    memset(Tprev, 0, sizeof(Tprev));
    memset(Tcur, 0, sizeof(Tcur));
    Tprev[0] = 1.0; mono[0] += cheb[0];
    Tcur[1]  = 1.0; mono[1] += cheb[1];
    for (int k = 2; k <= DEG; ++k) {
      double Tn[DEG + 1];
      memset(Tn, 0, sizeof(Tn));
      for (int j = 0; j <= k; ++j) {
        double v = -Tprev[j];
        if (j > 0) v += 2.0 * Tcur[j - 1];
        Tn[j] = v;
      }
      for (int j = 0; j <= k; ++j) mono[j] += cheb[k] * Tn[j];
      for (int j = 0; j <= DEG; ++j) { Tprev[j] = Tcur[j]; Tcur[j] = Tn[j]; }
    }
    for (int i = 0; i <= DEG; ++i) cf.a[i] = (float)mono[i];
    cf.cc = (float)cc; cf.inv_h = (float)(1.0 / hh);
  }

  dim3 grid(nmat), block(256);
  hipLaunchKernelGGL(logm_kernel, grid, block, 0, stream, X, Y, cf);
}

// Round 6
// 181.627 us; speedup vs baseline: 1.6487x; 1.1999x over previous
//
#include <hip/hip_runtime.h>
#include <math.h>
#include <string.h>

#define CDIM 64
#define LDSW 72   // row stride in bf16 elems (144 B): b128 frag reads measured conflict-free
#define DEG  5    // Chebyshev tail on [1,7.5] ~5.6e-3; Paterson-Stockmeyer s=2 -> 3 matmuls

struct Coefs { float a[DEG + 1]; float cc; float inv_h; };

typedef __attribute__((ext_vector_type(8)))  short short8;    // 8 bf16 = 4 VGPRs (MFMA A/B frag)
typedef __attribute__((ext_vector_type(16))) float floatx16;  // MFMA C/D

// Row-major hi/lo store of one fp32 as two bf16 (truncation split).
// Per instruction: half-wave writes 32 consecutive u16 of row q, other half
// row q+4 -> in-dword lane merge: 0 conflicts (measured R2).
__device__ __forceinline__ void st_hilo(unsigned short* __restrict__ Dh,
                                        unsigned short* __restrict__ Dl,
                                        int idx, float x) {
  const unsigned u = __builtin_bit_cast(unsigned, x);
  const float h = __builtin_bit_cast(float, u & 0xFFFF0000u);
  const float l = x - h;                       // exact
  const unsigned ul = __builtin_bit_cast(unsigned, l);
  Dh[idx] = (unsigned short)(u >> 16);
  Dl[idx] = (unsigned short)(ul >> 16);
}

// hi-only store with round-to-nearest (2^-9 err vs 2^-8 truncation).
__device__ __forceinline__ void st_h_rn(unsigned short* __restrict__ Dh,
                                        int idx, float x) {
  const unsigned u = __builtin_bit_cast(unsigned, x);
  Dh[idx] = (unsigned short)((u + 0x7FFFu + ((u >> 16) & 1u)) >> 16);
}

// Scalar hi/lo read back to f32 (~2^-17 rel error vs stored value).
__device__ __forceinline__ float ld_hilo(const unsigned short* __restrict__ Ph,
                                         const unsigned short* __restrict__ Pl,
                                         int idx) {
  const float h = __builtin_bit_cast(float, ((unsigned)Ph[idx]) << 16);
  const float l = __builtin_bit_cast(float, ((unsigned)Pl[idx]) << 16);
  return h + l;
}

struct Frags  { short8 h[4]; short8 l[4]; };   // hi+lo fragments = 32 VGPRs
struct FragsH { short8 h[4]; };                // hi-only fragments = 16 VGPRs

__device__ __forceinline__ void load_frags(const unsigned short* __restrict__ Ph,
                                           const unsigned short* __restrict__ Pl,
                                           int row, int ko, Frags* f) {
#pragma unroll
  for (int kk = 0; kk < 4; ++kk) {
    f->h[kk] = *(const short8*)(Ph + row * LDSW + kk * 16 + ko);
    f->l[kk] = *(const short8*)(Pl + row * LDSW + kk * 16 + ko);
  }
}

__device__ __forceinline__ void load_frags_h(const unsigned short* __restrict__ Ph,
                                             int row, int ko, FragsH* f) {
#pragma unroll
  for (int kk = 0; kk < 4; ++kk)
    f->h[kk] = *(const short8*)(Ph + row * LDSW + kk * 16 + ko);
}

// Single-chain h*h 32x32 tile product (downstream matmuls: dropped l-terms
// are ~2^-9-relative, scaled by small coefficients -> ~1e-3 output error).
__device__ __forceinline__ floatx16 mm_h(const FragsH& a, const FragsH& b) {
  floatx16 c;
#pragma unroll
  for (int i = 0; i < 16; ++i) c[i] = 0.0f;
#pragma unroll
  for (int kk = 0; kk < 4; ++kk)
    c = __builtin_amdgcn_mfma_f32_32x32x16_bf16(a.h[kk], b.h[kk], c, 0, 0, 0);
  return c;
}

__global__ void __launch_bounds__(256, 4)
logm_kernel(const float* __restrict__ X, float* __restrict__ Y, Coefs cf) {
  // Buffers: A(hi+lo) = M1 (never overwritten), Ch = M2 then Q1 (hi-only, RN).
  // 3 x 9216 B = 27.6 KB -> LDS allows 5 blocks/CU; regs sized to permit it
  // (mm1 peak ~85: fa full + fb slab-wise; mm2/mm3 peak ~76 with h-only frags).
  // R1/R4/R5 lesson: no LBAR asm barriers, no setprio, no extra live arrays.
  __shared__ __align__(16) unsigned short Ah[CDIM * LDSW], Al[CDIM * LDSW];
  __shared__ __align__(16) unsigned short Ch[CDIM * LDSW];

  const int tid  = threadIdx.x;
  const int lane = tid & 63;
  const int w    = tid >> 6;
  const int m    = blockIdx.x;

  const float* __restrict__ Xm = X + (size_t)m * (CDIM * CDIM);
  float* __restrict__ Ym       = Y + (size_t)m * (CDIM * CDIM);

  const int R    = (w >> 1) * 32;
  const int Cc   = (w & 1) * 32;
  const int l31  = lane & 31;
  const int half = lane >> 5;
  const int arow = R + l31;
  const int brow = Cc + l31;
  const int ko   = half * 8;
  const int col  = Cc + l31;
  int rows[16];  // C/D layout: row = (r&3) + 8*(r>>2) + 4*half  [verified m74/m101]
#pragma unroll
  for (int r = 0; r < 16; ++r) rows[r] = R + (r & 3) + 8 * (r >> 2) + 4 * half;

  // ---- stage: load X once in C-layout (coalesced 2x128B per instr), M1 -> A hi/lo ----
#pragma unroll
  for (int r = 0; r < 16; ++r) {
    float x = Xm[rows[r] * CDIM + col];
    if (rows[r] == col) x -= cf.cc;
    st_hilo(Ah, Al, rows[r] * LDSW + col, x * cf.inv_h);
  }
  __syncthreads();

  // ---- mm1: M2 = M1*M1 (full 3-chain compensation; feeds 2 more multiplies).
  //      fa loaded whole (h half reused as mm2's A-operand); fb slab-wise to
  //      cap the register peak. Branch-free: diagonal waves just re-read fa's
  //      rows via brow (broadcast-friendly, M1 symmetric). ----
  Frags fa;
  load_frags(Ah, Al, arow, ko, &fa);
  floatx16 c1, c2;
#pragma unroll
  for (int i = 0; i < 16; ++i) { c1[i] = 0.0f; c2[i] = 0.0f; }
#pragma unroll
  for (int kk = 0; kk < 4; ++kk) {
    const short8 fbh = *(const short8*)(Ah + brow * LDSW + kk * 16 + ko);
    const short8 fbl = *(const short8*)(Al + brow * LDSW + kk * 16 + ko);
    c1 = __builtin_amdgcn_mfma_f32_32x32x16_bf16(fa.h[kk], fbh, c1, 0, 0, 0);
    c2 = __builtin_amdgcn_mfma_f32_32x32x16_bf16(fa.h[kk], fbl, c2, 0, 0, 0);
    c2 = __builtin_amdgcn_mfma_f32_32x32x16_bf16(fa.l[kk], fbh, c2, 0, 0, 0);
  }
  floatx16 accM2;
#pragma unroll
  for (int i = 0; i < 16; ++i) accM2[i] = c1[i] + c2[i];
#pragma unroll
  for (int r = 0; r < 16; ++r) st_h_rn(Ch, rows[r] * LDSW + col, accM2[r]);
  __syncthreads();   // M2 (hi, RN) published; all A reads for mm1 done

  // ---- mm2: T = M1*M2 (h-only; fa.h reused, fa.l dead);
  //      Q1 = a5*T + a4*accM2(f32 exact) + a3*M1(hi/lo) + a2*I ----
  FragsH fah, fm2;
#pragma unroll
  for (int kk = 0; kk < 4; ++kk) fah.h[kk] = fa.h[kk];
  load_frags_h(Ch, brow, ko, &fm2);      // M2 B-operand via symmetry; kept for mm3
  floatx16 accT = mm_h(fah, fm2);
  __syncthreads();                       // all Ch (M2) cross-tile reads complete
#pragma unroll
  for (int r = 0; r < 16; ++r) {
    const int idx = rows[r] * LDSW + col;
    float q = cf.a[5] * accT[r] + cf.a[4] * accM2[r] + cf.a[3] * ld_hilo(Ah, Al, idx);
    if (rows[r] == col) q += cf.a[2];
    st_h_rn(Ch, idx, q);                 // Q1 over M2 (hi-only, RN)
  }
  __syncthreads();

  // ---- mm3: out = Q1*M2 (h-only) + a1*M1(hi/lo) + a0*I -> global ----
  FragsH fq1;
  load_frags_h(Ch, arow, ko, &fq1);
  floatx16 accF = mm_h(fq1, fm2);
#pragma unroll
  for (int r = 0; r < 16; ++r) {
    float p = accF[r] + cf.a[1] * ld_hilo(Ah, Al, rows[r] * LDSW + col);
    if (rows[r] == col) p += cf.a[0];
    Ym[rows[r] * CDIM + col] = p;        // 2x128B coalesced per instr
  }
}

extern "C" void kernel_launch(void* const* d_in, const int* in_sizes, int n_in,
                              void* d_out, int out_size, void* d_ws, size_t ws_size,
                              hipStream_t stream) {
  const float* X = (const float*)d_in[0];
  float* Y = (float*)d_out;
  const int nmat = in_sizes[0] / (CDIM * CDIM);

  // Chebyshev coefficients of log on [lo,hi] -> monomial basis in t=(x-cc)/hh.
  // Analytic: log(cc+hh*t) = log(A) - 2*sum_k z^k/k T_k(t),  z=(-cc+sqrt(cc^2-hh^2))/hh
  Coefs cf;
  {
    const double lo = 1.0, hi = 7.5;
    const double cc = 0.5 * (lo + hi), hh = 0.5 * (hi - lo);
    const double s  = sqrt(cc * cc - hh * hh);
    const double z  = (-cc + s) / hh;
    const double A  = 0.5 * (cc + s);
    double cheb[DEG + 1];
    cheb[0] = log(A);
    double zp = 1.0;
    for (int k = 1; k <= DEG; ++k) { zp *= z; cheb[k] = -2.0 * zp / (double)k; }
    double mono[DEG + 1], Tprev[DEG + 1], Tcur[DEG + 1];
    memset(mono, 0, sizeof(mono));
    memset(Tprev, 0, sizeof(Tprev));
    memset(Tcur, 0, sizeof(Tcur));
    Tprev[0] = 1.0; mono[0] += cheb[0];
    Tcur[1]  = 1.0; mono[1] += cheb[1];
    for (int k = 2; k <= DEG; ++k) {
      double Tn[DEG + 1];
      memset(Tn, 0, sizeof(Tn));
      for (int j = 0; j <= k; ++j) {
        double v = -Tprev[j];
        if (j > 0) v += 2.0 * Tcur[j - 1];
        Tn[j] = v;
      }
      for (int j = 0; j <= k; ++j) mono[j] += cheb[k] * Tn[j];
      for (int j = 0; j <= DEG; ++j) { Tprev[j] = Tcur[j]; Tcur[j] = Tn[j]; }
    }
    for (int i = 0; i <= DEG; ++i) cf.a[i] = (float)mono[i];
    cf.cc = (float)cc; cf.inv_h = (float)(1.0 / hh);
  }

  dim3 grid(nmat), block(256);
  hipLaunchKernelGGL(logm_kernel, grid, block, 0, stream, X, Y, cf);
}